// Round 2
// baseline (23635.611 us; speedup 1.0000x reference)
//
#include <hip/hip_runtime.h>
#include <hip/hip_bf16.h>

// Sizes fixed by the problem
#define BB 128
#define SS 1024
#define FF 512
#define HH 128
#define G3 384   // 3*H

// ---------------------------------------------------------------------------
// lengths: len[b] = #rows t with sum_f x[b,t,f] != 0
// ---------------------------------------------------------------------------
__global__ void zero_len_kernel(int* len) { len[threadIdx.x] = 0; }

__global__ void lengths_kernel(const float* __restrict__ x, int* __restrict__ len) {
    int wave = threadIdx.x >> 6;
    int lane = threadIdx.x & 63;
    long row = (long)blockIdx.x * 4 + wave;   // 0 .. 131071
    const float4* p = (const float4*)&x[row * FF + lane * 8];
    float4 v0 = p[0], v1 = p[1];
    float s = v0.x + v0.y + v0.z + v0.w + v1.x + v1.y + v1.z + v1.w;
    #pragma unroll
    for (int off = 32; off > 0; off >>= 1) s += __shfl_down(s, off, 64);
    if (lane == 0 && s != 0.0f) atomicAdd(&len[row >> 10], 1);
}

// rank[i] = stable rank under descending-length sort (ties -> lower index first)
__global__ void rank_kernel(const int* __restrict__ len, int* __restrict__ rank) {
    int i = threadIdx.x;
    int li = len[i];
    int r = 0;
    for (int jj = 0; jj < BB; jj++) {
        int lj = len[jj];
        if (lj > li || (lj == li && jj < i)) r++;
    }
    rank[i] = r;
}

// ---------------------------------------------------------------------------
// C[M,N] = A[M,K] @ B[N,K]^T + bias[N]   (fp32, 128x128 tile, 8x8/thread)
// ---------------------------------------------------------------------------
__global__ __launch_bounds__(256) void gemm_abt(
    const float* __restrict__ A, const float* __restrict__ B,
    const float* __restrict__ bias, float* __restrict__ C,
    int M, int N, int K)
{
    __shared__ float As[16][132];
    __shared__ float Bs[16][132];
    const int tid = threadIdx.x;
    const int tm0 = blockIdx.x * 128;
    const int tn0 = blockIdx.y * 128;
    const int row = tid >> 2;          // 0..63
    const int c4  = (tid & 3) * 4;     // 0,4,8,12
    const int ty  = tid >> 4;          // 0..15
    const int tx  = tid & 15;          // 0..15

    float acc[8][8];
    #pragma unroll
    for (int i = 0; i < 8; i++)
        #pragma unroll
        for (int j = 0; j < 8; j++) acc[i][j] = 0.0f;

    for (int k0 = 0; k0 < K; k0 += 16) {
        float4 av0 = *(const float4*)&A[(size_t)(tm0 + row)      * K + k0 + c4];
        float4 av1 = *(const float4*)&A[(size_t)(tm0 + row + 64) * K + k0 + c4];
        float4 bv0 = *(const float4*)&B[(size_t)(tn0 + row)      * K + k0 + c4];
        float4 bv1 = *(const float4*)&B[(size_t)(tn0 + row + 64) * K + k0 + c4];
        __syncthreads();
        As[c4 + 0][row] = av0.x; As[c4 + 1][row] = av0.y;
        As[c4 + 2][row] = av0.z; As[c4 + 3][row] = av0.w;
        As[c4 + 0][row + 64] = av1.x; As[c4 + 1][row + 64] = av1.y;
        As[c4 + 2][row + 64] = av1.z; As[c4 + 3][row + 64] = av1.w;
        Bs[c4 + 0][row] = bv0.x; Bs[c4 + 1][row] = bv0.y;
        Bs[c4 + 2][row] = bv0.z; Bs[c4 + 3][row] = bv0.w;
        Bs[c4 + 0][row + 64] = bv1.x; Bs[c4 + 1][row + 64] = bv1.y;
        Bs[c4 + 2][row + 64] = bv1.z; Bs[c4 + 3][row + 64] = bv1.w;
        __syncthreads();
        #pragma unroll
        for (int kk = 0; kk < 16; kk++) {
            float a[8], b[8];
            *(float4*)&a[0] = *(const float4*)&As[kk][ty * 8];
            *(float4*)&a[4] = *(const float4*)&As[kk][ty * 8 + 4];
            *(float4*)&b[0] = *(const float4*)&Bs[kk][tx * 8];
            *(float4*)&b[4] = *(const float4*)&Bs[kk][tx * 8 + 4];
            #pragma unroll
            for (int i = 0; i < 8; i++)
                #pragma unroll
                for (int j = 0; j < 8; j++)
                    acc[i][j] = fmaf(a[i], b[j], acc[i][j]);
        }
    }

    float bv[8];
    #pragma unroll
    for (int j = 0; j < 8; j++) bv[j] = bias[tn0 + tx * 8 + j];
    #pragma unroll
    for (int i = 0; i < 8; i++) {
        size_t crow = (size_t)(tm0 + ty * 8 + i) * N + tn0 + tx * 8;
        float4 o0, o1;
        o0.x = acc[i][0] + bv[0]; o0.y = acc[i][1] + bv[1];
        o0.z = acc[i][2] + bv[2]; o0.w = acc[i][3] + bv[3];
        o1.x = acc[i][4] + bv[4]; o1.y = acc[i][5] + bv[5];
        o1.z = acc[i][6] + bv[6]; o1.w = acc[i][7] + bv[7];
        *(float4*)&C[crow]     = o0;
        *(float4*)&C[crow + 4] = o1;
    }
}

// ---------------------------------------------------------------------------
// GRU recurrence, v2. One block (512 thr = 8 waves) per batch row.
// Thread (j = tid>>2, kq = tid&3): owns Whh[{r,z,n} rows j][kq*32 .. +32)
// = 96 floats in VGPRs (fits: launch_bounds(512,2) -> <=256 VGPR, no spill).
// h broadcast via double-buffered LDS; per-kq rotated read order so the 4
// distinct broadcast addresses hit disjoint bank groups (conflict-free).
// Reduction over kq via 2x shfl_xor. Fast v_exp/v_rcp sigmoid+tanh.
// FINAL==0: coalesced lagged write of h_t (wave 1, float4).
// FINAL==1: masked mean -> out[rank[b],:].
// ---------------------------------------------------------------------------
__device__ __forceinline__ float fast_sigmoid(float x) {
    return __builtin_amdgcn_rcpf(1.0f + __expf(-x));
}
__device__ __forceinline__ float fast_tanh(float x) {
    // 1 - 2/(1+exp(2x)); correct limits at +-inf
    return 1.0f - 2.0f * __builtin_amdgcn_rcpf(1.0f + __expf(2.0f * x));
}

template<int FINAL>
__global__ __launch_bounds__(512, 2) void gru_rec(
    const float* __restrict__ xg,    // [B,S,3H]
    const float* __restrict__ Whh,   // [3H,H]
    const float* __restrict__ bhh,   // [3H]
    float* __restrict__ h_out,       // [B,S,H] (FINAL=0) or [B,H] (FINAL=1)
    const int* __restrict__ len,
    const int* __restrict__ rank)
{
    const int b   = blockIdx.x;
    const int tid = threadIdx.x;
    const int j   = tid >> 2;     // 0..127 output lane
    const int kq  = tid & 3;      // K-quarter (32 elems)

    __shared__ __align__(16) float h_lds[2][HH];

    // 3 gates x 32 weights in VGPRs
    float4 wv[3][8];
    #pragma unroll
    for (int g = 0; g < 3; g++) {
        const float4* wr = (const float4*)&Whh[(size_t)(g * HH + j) * HH + kq * 32];
        #pragma unroll
        for (int q = 0; q < 8; q++) wv[g][q] = wr[q];
    }
    float b_r = 0.f, b_z = 0.f, b_n = 0.f;
    if (kq == 0) { b_r = bhh[j]; b_z = bhh[HH + j]; b_n = bhh[2 * HH + j]; }
    const float* xgb = xg + (size_t)b * SS * G3;

    if (tid < 2 * HH) ((float*)h_lds)[tid] = 0.0f;
    float hprev = 0.0f, osum = 0.0f;
    const int L = FINAL ? len[b] : 0;

    // prefetch xg for t=0 (only gate lanes need it)
    float xr = 0.f, xz = 0.f, xn = 0.f;
    if (kq == 0) { xr = xgb[j]; xz = xgb[HH + j]; xn = xgb[2 * HH + j]; }
    __syncthreads();

    for (int t = 0; t < SS; t++) {
        // lagged coalesced global write of h_{t-1} (wave 1)
        if (!FINAL && t > 0 && tid >= 64 && tid < 96) {
            int c = tid - 64;
            float4 hv = ((const float4*)h_lds[t & 1])[c];
            *(float4*)&h_out[((size_t)b * SS + (t - 1)) * HH + c * 4] = hv;
        }
        // prefetch xg for t+1
        float nxr = 0.f, nxz = 0.f, nxn = 0.f;
        if (kq == 0 && t + 1 < SS) {
            const float* p = xgb + (size_t)(t + 1) * G3;
            nxr = p[j]; nxz = p[HH + j]; nxn = p[2 * HH + j];
        }
        // matvec: 3 gates x 32 elems, float4 component chains (12 indep chains)
        const float4* h4 = (const float4*)h_lds[t & 1];
        float4 ar = {0,0,0,0}, az = {0,0,0,0}, an = {0,0,0,0};
        #pragma unroll
        for (int q = 0; q < 8; q++) {
            int qq = (q + 2 * kq) & 7;          // bank-staggered order per kq
            float4 hv = h4[kq * 8 + qq];
            float4 w0 = wv[0][qq], w1 = wv[1][qq], w2 = wv[2][qq];
            ar.x = fmaf(w0.x, hv.x, ar.x); ar.y = fmaf(w0.y, hv.y, ar.y);
            ar.z = fmaf(w0.z, hv.z, ar.z); ar.w = fmaf(w0.w, hv.w, ar.w);
            az.x = fmaf(w1.x, hv.x, az.x); az.y = fmaf(w1.y, hv.y, az.y);
            az.z = fmaf(w1.z, hv.z, az.z); az.w = fmaf(w1.w, hv.w, az.w);
            an.x = fmaf(w2.x, hv.x, an.x); an.y = fmaf(w2.y, hv.y, an.y);
            an.z = fmaf(w2.z, hv.z, an.z); an.w = fmaf(w2.w, hv.w, an.w);
        }
        float a0 = (ar.x + ar.y) + (ar.z + ar.w);
        float a1 = (az.x + az.y) + (az.z + az.w);
        float a2 = (an.x + an.y) + (an.z + an.w);
        a0 += __shfl_xor(a0, 1, 64); a1 += __shfl_xor(a1, 1, 64); a2 += __shfl_xor(a2, 1, 64);
        a0 += __shfl_xor(a0, 2, 64); a1 += __shfl_xor(a1, 2, 64); a2 += __shfl_xor(a2, 2, 64);
        if (kq == 0) {
            float r = fast_sigmoid(xr + a0 + b_r);
            float z = fast_sigmoid(xz + a1 + b_z);
            float n = fast_tanh(xn + r * (a2 + b_n));
            float h = (1.0f - z) * n + z * hprev;
            hprev = h;
            h_lds[(t + 1) & 1][j] = h;
            if (FINAL) { if (t < L) osum += h; }
        }
        xr = nxr; xz = nxz; xn = nxn;
        __syncthreads();
    }
    if (!FINAL && tid >= 64 && tid < 96) {
        int c = tid - 64;
        float4 hv = ((const float4*)h_lds[SS & 1])[c];
        *(float4*)&h_out[((size_t)b * SS + (SS - 1)) * HH + c * 4] = hv;
    }
    if (FINAL && kq == 0) {
        h_out[(size_t)rank[b] * HH + j] = osum * (1.0f / (float)SS);
    }
}

// ---------------------------------------------------------------------------
extern "C" void kernel_launch(void* const* d_in, const int* in_sizes, int n_in,
                              void* d_out, int out_size, void* d_ws, size_t ws_size,
                              hipStream_t stream) {
    const float* x    = (const float*)d_in[0];
    const float* Wp   = (const float*)d_in[1];
    const float* bp   = (const float*)d_in[2];
    const float* Wih0 = (const float*)d_in[3];
    const float* Whh0 = (const float*)d_in[4];
    const float* bih0 = (const float*)d_in[5];
    const float* bhh0 = (const float*)d_in[6];
    const float* Wih1 = (const float*)d_in[7];
    const float* Whh1 = (const float*)d_in[8];
    const float* bih1 = (const float*)d_in[9];
    const float* bhh1 = (const float*)d_in[10];
    float* out = (float*)d_out;

    // workspace layout: [len 128 int][rank 128 int] ... 4KB ... proj/h1 (64MB), xg (192MB)
    int* len  = (int*)d_ws;
    int* rank = len + 128;
    float* proj = (float*)((char*)d_ws + 4096);                  // [B*S, H]  also reused as h1
    float* xgb  = proj + (size_t)BB * SS * HH;                   // [B*S, 3H]

    // 1) lengths + rank
    zero_len_kernel<<<1, 128, 0, stream>>>(len);
    lengths_kernel<<<(BB * SS) / 4, 256, 0, stream>>>(x, len);
    rank_kernel<<<1, 128, 0, stream>>>(len, rank);

    // 2) proj = x @ Wp^T + bp       [131072,512] x [128,512]^T
    gemm_abt<<<dim3(BB * SS / 128, HH / 128), 256, 0, stream>>>(x, Wp, bp, proj,
                                                               BB * SS, HH, FF);
    // 3) xg0 = proj @ Wih0^T + bih0 [131072,128] x [384,128]^T
    gemm_abt<<<dim3(BB * SS / 128, G3 / 128), 256, 0, stream>>>(proj, Wih0, bih0, xgb,
                                                                BB * SS, G3, HH);
    // 4) layer-1 recurrence -> h1 (into proj region; proj is dead now)
    gru_rec<0><<<BB, 512, 0, stream>>>(xgb, Whh0, bhh0, proj, len, rank);

    // 5) xg1 = h1 @ Wih1^T + bih1 (overwrite xg region)
    gemm_abt<<<dim3(BB * SS / 128, G3 / 128), 256, 0, stream>>>(proj, Wih1, bih1, xgb,
                                                                BB * SS, G3, HH);
    // 6) layer-2 recurrence + masked mean -> out at sorted rank
    gru_rec<1><<<BB, 512, 0, stream>>>(xgb, Whh1, bhh1, out, len, rank);
}

// Round 3
// 2347.443 us; speedup vs baseline: 10.0687x; 10.0687x over previous
//
#include <hip/hip_runtime.h>
#include <hip/hip_bf16.h>

// Sizes fixed by the problem
#define BB 128
#define SS 1024
#define FF 512
#define HH 128
#define G3 384   // 3*H

// ---------------------------------------------------------------------------
// lengths: len[b] = #rows t with sum_f x[b,t,f] != 0
// ---------------------------------------------------------------------------
__global__ void zero_len_kernel(int* len) { len[threadIdx.x] = 0; }

__global__ void lengths_kernel(const float* __restrict__ x, int* __restrict__ len) {
    int wave = threadIdx.x >> 6;
    int lane = threadIdx.x & 63;
    long row = (long)blockIdx.x * 4 + wave;   // 0 .. 131071
    const float4* p = (const float4*)&x[row * FF + lane * 8];
    float4 v0 = p[0], v1 = p[1];
    float s = v0.x + v0.y + v0.z + v0.w + v1.x + v1.y + v1.z + v1.w;
    #pragma unroll
    for (int off = 32; off > 0; off >>= 1) s += __shfl_down(s, off, 64);
    if (lane == 0 && s != 0.0f) atomicAdd(&len[row >> 10], 1);
}

// rank[i] = stable rank under descending-length sort (ties -> lower index first)
__global__ void rank_kernel(const int* __restrict__ len, int* __restrict__ rank) {
    int i = threadIdx.x;
    int li = len[i];
    int r = 0;
    for (int jj = 0; jj < BB; jj++) {
        int lj = len[jj];
        if (lj > li || (lj == li && jj < i)) r++;
    }
    rank[i] = r;
}

// ---------------------------------------------------------------------------
// C[M,N] = A[M,K] @ B[N,K]^T + bias[N]   (fp32, 128x128 tile, 8x8/thread)
// ---------------------------------------------------------------------------
__global__ __launch_bounds__(256) void gemm_abt(
    const float* __restrict__ A, const float* __restrict__ B,
    const float* __restrict__ bias, float* __restrict__ C,
    int M, int N, int K)
{
    __shared__ float As[16][132];
    __shared__ float Bs[16][132];
    const int tid = threadIdx.x;
    const int tm0 = blockIdx.x * 128;
    const int tn0 = blockIdx.y * 128;
    const int row = tid >> 2;          // 0..63
    const int c4  = (tid & 3) * 4;     // 0,4,8,12
    const int ty  = tid >> 4;          // 0..15
    const int tx  = tid & 15;          // 0..15

    float acc[8][8];
    #pragma unroll
    for (int i = 0; i < 8; i++)
        #pragma unroll
        for (int j = 0; j < 8; j++) acc[i][j] = 0.0f;

    for (int k0 = 0; k0 < K; k0 += 16) {
        float4 av0 = *(const float4*)&A[(size_t)(tm0 + row)      * K + k0 + c4];
        float4 av1 = *(const float4*)&A[(size_t)(tm0 + row + 64) * K + k0 + c4];
        float4 bv0 = *(const float4*)&B[(size_t)(tn0 + row)      * K + k0 + c4];
        float4 bv1 = *(const float4*)&B[(size_t)(tn0 + row + 64) * K + k0 + c4];
        __syncthreads();
        As[c4 + 0][row] = av0.x; As[c4 + 1][row] = av0.y;
        As[c4 + 2][row] = av0.z; As[c4 + 3][row] = av0.w;
        As[c4 + 0][row + 64] = av1.x; As[c4 + 1][row + 64] = av1.y;
        As[c4 + 2][row + 64] = av1.z; As[c4 + 3][row + 64] = av1.w;
        Bs[c4 + 0][row] = bv0.x; Bs[c4 + 1][row] = bv0.y;
        Bs[c4 + 2][row] = bv0.z; Bs[c4 + 3][row] = bv0.w;
        Bs[c4 + 0][row + 64] = bv1.x; Bs[c4 + 1][row + 64] = bv1.y;
        Bs[c4 + 2][row + 64] = bv1.z; Bs[c4 + 3][row + 64] = bv1.w;
        __syncthreads();
        #pragma unroll
        for (int kk = 0; kk < 16; kk++) {
            float a[8], b[8];
            *(float4*)&a[0] = *(const float4*)&As[kk][ty * 8];
            *(float4*)&a[4] = *(const float4*)&As[kk][ty * 8 + 4];
            *(float4*)&b[0] = *(const float4*)&Bs[kk][tx * 8];
            *(float4*)&b[4] = *(const float4*)&Bs[kk][tx * 8 + 4];
            #pragma unroll
            for (int i = 0; i < 8; i++)
                #pragma unroll
                for (int j = 0; j < 8; j++)
                    acc[i][j] = fmaf(a[i], b[j], acc[i][j]);
        }
    }

    float bv[8];
    #pragma unroll
    for (int j = 0; j < 8; j++) bv[j] = bias[tn0 + tx * 8 + j];
    #pragma unroll
    for (int i = 0; i < 8; i++) {
        size_t crow = (size_t)(tm0 + ty * 8 + i) * N + tn0 + tx * 8;
        float4 o0, o1;
        o0.x = acc[i][0] + bv[0]; o0.y = acc[i][1] + bv[1];
        o0.z = acc[i][2] + bv[2]; o0.w = acc[i][3] + bv[3];
        o1.x = acc[i][4] + bv[4]; o1.y = acc[i][5] + bv[5];
        o1.z = acc[i][6] + bv[6]; o1.w = acc[i][7] + bv[7];
        *(float4*)&C[crow]     = o0;
        *(float4*)&C[crow + 4] = o1;
    }
}

// ---------------------------------------------------------------------------
// GRU recurrence, v3. One block (512 thr = 8 waves) per batch row.
// Thread (j = tid>>2, kq = tid&3): owns Whh[{r,z,n} rows j][kq*32 .. +32)
// = 96 floats in VGPRs.
// CRITICAL (rule #20 / round-2 post-mortem): ALL register-array indices are
// compile-time constants. The per-kq bank stagger is applied by PRE-ROTATING
// the weight fragments at load time (runtime index into *global memory* only);
// the inner loop then uses wv[g][q] with static q and puts the rotation into
// the LDS *address* (runtime LDS addresses are fine).
// h broadcast via double-buffered LDS; reduction over kq via 2x shfl_xor;
// fast v_exp/v_rcp sigmoid+tanh.
// FINAL==0: coalesced lagged write of h_t (wave 1, float4).
// FINAL==1: masked mean -> out[rank[b],:].
// ---------------------------------------------------------------------------
__device__ __forceinline__ float fast_sigmoid(float x) {
    return __builtin_amdgcn_rcpf(1.0f + __expf(-x));
}
__device__ __forceinline__ float fast_tanh(float x) {
    // 1 - 2/(1+exp(2x)); correct limits at +-inf
    return 1.0f - 2.0f * __builtin_amdgcn_rcpf(1.0f + __expf(2.0f * x));
}

template<int FINAL>
__global__ __launch_bounds__(512, 2) void gru_rec(
    const float* __restrict__ xg,    // [B,S,3H]
    const float* __restrict__ Whh,   // [3H,H]
    const float* __restrict__ bhh,   // [3H]
    float* __restrict__ h_out,       // [B,S,H] (FINAL=0) or [B,H] (FINAL=1)
    const int* __restrict__ len,
    const int* __restrict__ rank)
{
    const int b   = blockIdx.x;
    const int tid = threadIdx.x;
    const int j   = tid >> 2;     // 0..127 output lane
    const int kq  = tid & 3;      // K-quarter (32 elems)

    __shared__ __align__(16) float h_lds[2][HH];

    // 3 gates x 32 weights in VGPRs, pre-rotated by 2*kq float4-slots
    float4 wv[3][8];
    #pragma unroll
    for (int g = 0; g < 3; g++) {
        const float4* wr = (const float4*)&Whh[(size_t)(g * HH + j) * HH + kq * 32];
        #pragma unroll
        for (int q = 0; q < 8; q++) wv[g][q] = wr[(q + 2 * kq) & 7];  // runtime idx into GLOBAL mem only
    }
    float b_r = 0.f, b_z = 0.f, b_n = 0.f;
    if (kq == 0) { b_r = bhh[j]; b_z = bhh[HH + j]; b_n = bhh[2 * HH + j]; }
    const float* xgb = xg + (size_t)b * SS * G3;

    if (tid < 2 * HH) ((float*)h_lds)[tid] = 0.0f;
    float hprev = 0.0f, osum = 0.0f;
    const int L = FINAL ? len[b] : 0;

    // prefetch xg for t=0 (only gate lanes need it)
    float xr = 0.f, xz = 0.f, xn = 0.f;
    if (kq == 0) { xr = xgb[j]; xz = xgb[HH + j]; xn = xgb[2 * HH + j]; }
    __syncthreads();

    for (int t = 0; t < SS; t++) {
        // lagged coalesced global write of h_{t-1} (wave 1)
        if (!FINAL && t > 0 && tid >= 64 && tid < 96) {
            int c = tid - 64;
            float4 hv = ((const float4*)h_lds[t & 1])[c];
            *(float4*)&h_out[((size_t)b * SS + (t - 1)) * HH + c * 4] = hv;
        }
        // prefetch xg for t+1
        float nxr = 0.f, nxz = 0.f, nxn = 0.f;
        if (kq == 0 && t + 1 < SS) {
            const float* p = xgb + (size_t)(t + 1) * G3;
            nxr = p[j]; nxz = p[HH + j]; nxn = p[2 * HH + j];
        }
        // matvec: 3 gates x 32 elems; LDS address carries the stagger, the
        // register arrays are indexed with the static q.
        const float4* h4 = (const float4*)h_lds[t & 1];
        float4 ar = {0,0,0,0}, az = {0,0,0,0}, an = {0,0,0,0};
        #pragma unroll
        for (int q = 0; q < 8; q++) {
            float4 hv = h4[kq * 8 + ((q + 2 * kq) & 7)];   // runtime LDS addr: OK
            float4 w0 = wv[0][q], w1 = wv[1][q], w2 = wv[2][q];  // static reg idx
            ar.x = fmaf(w0.x, hv.x, ar.x); ar.y = fmaf(w0.y, hv.y, ar.y);
            ar.z = fmaf(w0.z, hv.z, ar.z); ar.w = fmaf(w0.w, hv.w, ar.w);
            az.x = fmaf(w1.x, hv.x, az.x); az.y = fmaf(w1.y, hv.y, az.y);
            az.z = fmaf(w1.z, hv.z, az.z); az.w = fmaf(w1.w, hv.w, az.w);
            an.x = fmaf(w2.x, hv.x, an.x); an.y = fmaf(w2.y, hv.y, an.y);
            an.z = fmaf(w2.z, hv.z, an.z); an.w = fmaf(w2.w, hv.w, an.w);
        }
        float a0 = (ar.x + ar.y) + (ar.z + ar.w);
        float a1 = (az.x + az.y) + (az.z + az.w);
        float a2 = (an.x + an.y) + (an.z + an.w);
        a0 += __shfl_xor(a0, 1, 64); a1 += __shfl_xor(a1, 1, 64); a2 += __shfl_xor(a2, 1, 64);
        a0 += __shfl_xor(a0, 2, 64); a1 += __shfl_xor(a1, 2, 64); a2 += __shfl_xor(a2, 2, 64);
        if (kq == 0) {
            float r = fast_sigmoid(xr + a0 + b_r);
            float z = fast_sigmoid(xz + a1 + b_z);
            float n = fast_tanh(xn + r * (a2 + b_n));
            float h = (1.0f - z) * n + z * hprev;
            hprev = h;
            h_lds[(t + 1) & 1][j] = h;
            if (FINAL) { if (t < L) osum += h; }
        }
        xr = nxr; xz = nxz; xn = nxn;
        __syncthreads();
    }
    if (!FINAL && tid >= 64 && tid < 96) {
        int c = tid - 64;
        float4 hv = ((const float4*)h_lds[SS & 1])[c];
        *(float4*)&h_out[((size_t)b * SS + (SS - 1)) * HH + c * 4] = hv;
    }
    if (FINAL && kq == 0) {
        h_out[(size_t)rank[b] * HH + j] = osum * (1.0f / (float)SS);
    }
}

// ---------------------------------------------------------------------------
extern "C" void kernel_launch(void* const* d_in, const int* in_sizes, int n_in,
                              void* d_out, int out_size, void* d_ws, size_t ws_size,
                              hipStream_t stream) {
    const float* x    = (const float*)d_in[0];
    const float* Wp   = (const float*)d_in[1];
    const float* bp   = (const float*)d_in[2];
    const float* Wih0 = (const float*)d_in[3];
    const float* Whh0 = (const float*)d_in[4];
    const float* bih0 = (const float*)d_in[5];
    const float* bhh0 = (const float*)d_in[6];
    const float* Wih1 = (const float*)d_in[7];
    const float* Whh1 = (const float*)d_in[8];
    const float* bih1 = (const float*)d_in[9];
    const float* bhh1 = (const float*)d_in[10];
    float* out = (float*)d_out;

    // workspace layout: [len 128 int][rank 128 int] ... 4KB ... proj/h1 (64MB), xg (192MB)
    int* len  = (int*)d_ws;
    int* rank = len + 128;
    float* proj = (float*)((char*)d_ws + 4096);                  // [B*S, H]  also reused as h1
    float* xgb  = proj + (size_t)BB * SS * HH;                   // [B*S, 3H]

    // 1) lengths + rank
    zero_len_kernel<<<1, 128, 0, stream>>>(len);
    lengths_kernel<<<(BB * SS) / 4, 256, 0, stream>>>(x, len);
    rank_kernel<<<1, 128, 0, stream>>>(len, rank);

    // 2) proj = x @ Wp^T + bp       [131072,512] x [128,512]^T
    gemm_abt<<<dim3(BB * SS / 128, HH / 128), 256, 0, stream>>>(x, Wp, bp, proj,
                                                               BB * SS, HH, FF);
    // 3) xg0 = proj @ Wih0^T + bih0 [131072,128] x [384,128]^T
    gemm_abt<<<dim3(BB * SS / 128, G3 / 128), 256, 0, stream>>>(proj, Wih0, bih0, xgb,
                                                                BB * SS, G3, HH);
    // 4) layer-1 recurrence -> h1 (into proj region; proj is dead now)
    gru_rec<0><<<BB, 512, 0, stream>>>(xgb, Whh0, bhh0, proj, len, rank);

    // 5) xg1 = h1 @ Wih1^T + bih1 (overwrite xg region)
    gemm_abt<<<dim3(BB * SS / 128, G3 / 128), 256, 0, stream>>>(proj, Wih1, bih1, xgb,
                                                                BB * SS, G3, HH);
    // 6) layer-2 recurrence + masked mean -> out at sorted rank
    gru_rec<1><<<BB, 512, 0, stream>>>(xgb, Whh1, bhh1, out, len, rank);
}